// Round 17
// baseline (106.844 us; speedup 1.0000x reference)
//
#include <hip/hip_runtime.h>
#include <hip/hip_bf16.h>
#include <stdint.h>

// Problem constants
#define NB 8
#define NP 225      // patches per image
#define PGRID 15    // 15x15 patch grid
#define DH 256      // hidden
#define DIN 130     // per-node feature dim

typedef _Float16 f16x8 __attribute__((ext_vector_type(8)));   // 8 f16 = 4 VGPRs
typedef float    f32x4 __attribute__((ext_vector_type(4)));

static __device__ __forceinline__ float lrelu(float x) { return fmaxf(x, 0.01f * x); }

// ---------------------------------------------------------------------------
// K1 (fused prep): blocks 0..359 = pool+patch+U/V projection (f32 math, f16
// store) + accg zeroing; blocks 360..391 = W1 repack to fragment-linear f16.
__global__ void prep_kernel(const float* __restrict__ x, const float* __restrict__ W0,
                            const float* __restrict__ b0, const float* __restrict__ W1,
                            _Float16* __restrict__ U, _Float16* __restrict__ V,
                            _Float16* __restrict__ W1F, float* __restrict__ accg) {
    int blk = blockIdx.x;
    if (blk >= 360) {
        int t = (blk - 360) * 256 + threadIdx.x;   // 8192 threads = 128 slots * 64 lanes
        int slot = t >> 6, l = t & 63;
        int nf = slot >> 3, ks = slot & 7;
        int n = nf * 16 + (l & 15);
        int kb = l >> 4;
        f16x8 wv;
        #pragma unroll
        for (int e = 0; e < 8; ++e) {
            int k = ks * 32 + kb * 8 + e;
            wv[e] = (_Float16)W1[k * DH + n];
        }
        reinterpret_cast<f16x8*>(W1F)[t] = wv;
        return;
    }
    int bb = blk / 45;
    int p0 = (blk % 45) * 5;
    if (blk % 45 == 0) accg[bb * DH + threadIdx.x] = 0.0f;   // replaces memset
    __shared__ float fl[5][DIN];
    int t = threadIdx.x;
    for (int idx = t; idx < 5 * DIN; idx += 256) {
        int pp = idx / DIN, f = idx % DIN;
        int p = p0 + pp;
        int r = p / PGRID, c = p % PGRID;
        float val;
        if (f < 128) {
            int ch = f >> 2, q = f & 3, ki = q >> 1, kj = q & 1;
            int R = r + ki, C = c + kj;                 // pooled coords (0..15)
            const float* xp = x + (((size_t)bb * 32 + ch) * 32 + 2 * R) * 32 + 2 * C;
            val = 0.25f * (xp[0] + xp[1] + xp[32] + xp[33]);
        } else {
            val = (f == 128) ? (float)(c - 7) : (float)(r - 7);  // cx, cy
        }
        fl[pp][f] = val;
    }
    __syncthreads();
    int n = t;  // 0..255
    float u[5] = {0, 0, 0, 0, 0}, v[5] = {0, 0, 0, 0, 0};
    for (int k = 0; k < DIN; ++k) {
        float wa = W0[k * DH + n];
        float wb = W0[(DIN + k) * DH + n];
        #pragma unroll
        for (int pp = 0; pp < 5; ++pp) {
            float f = fl[pp][k];
            u[pp] = fmaf(f, wa, u[pp]);
            v[pp] = fmaf(f, wb, v[pp]);
        }
    }
    float bb0 = b0[n];
    #pragma unroll
    for (int pp = 0; pp < 5; ++pp) {
        size_t base = ((size_t)bb * NP + p0 + pp) * DH + n;
        U[base] = (_Float16)(u[pp] + bb0);  // fold b0 into U
        V[base] = (_Float16)v[pp];
    }
}

// ---------------------------------------------------------------------------
// K2: main relational GEMM + reduce — R12 (champion, 65.7us) with the U-LDS
// stream removed. R12's LDS/block-iter = A-writes 32 + A-reads 128 + U-reads
// 64 b128; the U-reads are i-loop-invariant (U depends on j,k only) but the
// compiler can't hoist LDS reads across barriers. Fix: lane loads its 8 U
// frags ONCE into registers (uf[8], 32 regs) from global L2; Upad deleted.
// LDS 224 -> 160 b128/block-iter; build = pure VALU + ds_write.
// Schedule lesson (R6,R7,R13,R14,R15,R16 all regressed): keep the plain
// 2-barrier loop; no pins, no dbuf, no role-split.
__global__ __launch_bounds__(256, 2) void main_kernel(
        const _Float16* __restrict__ U, const _Float16* __restrict__ V,
        const _Float16* __restrict__ W1F, const float* __restrict__ b1,
        float* __restrict__ accg) {
    __shared__ f16x8 Af[2048];            // 32 KB: [mf(4)][ks(8)][lane(64)] x 16B
    __shared__ _Float16 Vlds[28 * 256];   // 14 KB: chunk's V rows
    const int JT = 15, CHUNKS = 9, TILESPC = 7;  // 9*7=63 >= 57 i-tiles
    int blk = blockIdx.x;
    int bb = blk / (JT * CHUNKS);
    int rem = blk % (JT * CHUNKS);
    int jt = rem / CHUNKS, ch = rem % CHUNKS;
    int j0 = jt * 16;
    int tile0 = ch * TILESPC;
    int nt = min(TILESPC, 57 - tile0);
    int t = threadIdx.x, l = t & 63, w = t >> 6;

    // ---- DMA chunk V rows to LDS: 28 rows x 512B (tail reads ws garbage;
    // masked in epilogue by the wave-uniform i<NP skip)
    {
        const _Float16* Vsrc = V + ((size_t)bb * NP + tile0 * 4) * DH;
        for (int q = w * 4; q < 14 && q < w * 4 + 4; ++q) {
            __builtin_amdgcn_global_load_lds(
                (const __attribute__((address_space(1))) void*)(Vsrc + q * 512 + (size_t)l * 8),
                (__attribute__((address_space(3))) void*)(&Vlds[q * 512]),
                16, 0, 0);
        }
    }
    // ---- U fragments for this lane, ONCE into registers (i-loop invariant).
    // lane l covers j = j0+(l&15), k = kb*8 + ks*32 (kb = l>>4).
    int kb = l >> 4;
    f16x8 uf[8];
    {
        int jc = j0 + (l & 15); if (jc >= NP) jc = NP - 1;   // jmask kills later
        const _Float16* Ur = U + ((size_t)bb * NP + jc) * DH + kb * 8;
        #pragma unroll
        for (int ks = 0; ks < 8; ++ks)
            uf[ks] = *reinterpret_cast<const f16x8*>(Ur + ks * 32);
    }
    // ---- B fragments (wave's N=64 slice): 32 frags = 128 regs
    f16x8 bv[4][8];
    const f16x8* Bp = reinterpret_cast<const f16x8*>(W1F);
    #pragma unroll
    for (int nf = 0; nf < 4; ++nf)
        #pragma unroll
        for (int ks = 0; ks < 8; ++ks)
            bv[nf][ks] = Bp[((w * 4 + nf) * 8 + ks) * 64 + l];
    float b1v[4];
    #pragma unroll
    for (int nf = 0; nf < 4; ++nf) b1v[nf] = b1[w * 64 + nf * 16 + (l & 15)];
    int rowg = l >> 4;
    float jmask[4];
    #pragma unroll
    for (int r = 0; r < 4; ++r) jmask[r] = (j0 + rowg * 4 + r) < NP ? 1.0f : 0.0f;
    float psum[4] = {0.f, 0.f, 0.f, 0.f};
    __syncthreads();   // drains vmcnt (Vlds DMA)

    for (int itl = 0; itl < nt; ++itl) {
        int i0 = (tile0 + itl) * 4;
        const f16x8* Vrow = reinterpret_cast<const f16x8*>(&Vlds[(itl * 4 + w) * 256]);
        if (itl) __syncthreads();   // prev iter's A reads done before overwrite

        // ---- build A: wave w builds mf=w, 8 ks slots (pure VALU + ds_write)
        #pragma unroll
        for (int ks = 0; ks < 8; ++ks) {
            f16x8 vv = Vrow[ks * 4 + kb];
            f16x8 s  = uf[ks] + vv;
            f16x8 a  = __builtin_elementwise_max(s, s * (_Float16)0.01f);
            Af[(w * 8 + ks) * 64 + l] = a;
        }
        __syncthreads();

        // ---- MFMA: acc init = b1 (col = lane&15, same for all rows)
        f32x4 acc[4][4];
        #pragma unroll
        for (int mf = 0; mf < 4; ++mf)
            #pragma unroll
            for (int nf = 0; nf < 4; ++nf)
                acc[mf][nf] = (f32x4){b1v[nf], b1v[nf], b1v[nf], b1v[nf]};
        #pragma unroll
        for (int ks = 0; ks < 8; ++ks) {
            f16x8 av[4];
            #pragma unroll
            for (int mf = 0; mf < 4; ++mf) av[mf] = Af[(mf * 8 + ks) * 64 + l];
            #pragma unroll
            for (int mf = 0; mf < 4; ++mf)
                #pragma unroll
                for (int nf = 0; nf < 4; ++nf)
                    acc[mf][nf] = __builtin_amdgcn_mfma_f32_16x16x32_f16(
                        av[mf], bv[nf][ks], acc[mf][nf], 0, 0, 0);
        }

        // ---- epilogue: lrelu + jmask-fma row-sum (wave-uniform mf skip)
        #pragma unroll
        for (int mf = 0; mf < 4; ++mf) {
            if (i0 + mf < NP) {
                #pragma unroll
                for (int r = 0; r < 4; ++r) {
                    #pragma unroll
                    for (int nf = 0; nf < 4; ++nf) {
                        float a = acc[mf][nf][r];
                        float h = fmaxf(a, 0.01f * a);
                        psum[nf] = fmaf(h, jmask[r], psum[nf]);
                    }
                }
            }
        }
    }

    // ---- block-level reduce + one atomicAdd set
    #pragma unroll
    for (int nf = 0; nf < 4; ++nf) {
        psum[nf] += __shfl_xor(psum[nf], 16);
        psum[nf] += __shfl_xor(psum[nf], 32);
    }
    if (l < 16) {
        #pragma unroll
        for (int nf = 0; nf < 4; ++nf)
            atomicAdd(&accg[bb * DH + w * 64 + nf * 16 + l], psum[nf]);
    }
}

// ---------------------------------------------------------------------------
// K3: out[b,o] = (accg[b,:]/P^2) @ Wout + bout
__global__ void out_kernel(const float* __restrict__ accg, const float* __restrict__ Wout,
                           const float* __restrict__ bout, float* __restrict__ out) {
    int bb = blockIdx.x;
    int o = threadIdx.x;  // 0..127
    float s = 0.f;
    for (int n = 0; n < DH; ++n)
        s = fmaf(accg[bb * DH + n], Wout[n * 128 + o], s);
    out[bb * 128 + o] = s * (1.0f / 50625.0f) + bout[o];
}

// ---------------------------------------------------------------------------
extern "C" void kernel_launch(void* const* d_in, const int* in_sizes, int n_in,
                              void* d_out, int out_size, void* d_ws, size_t ws_size,
                              hipStream_t stream) {
    const float* x    = (const float*)d_in[0];
    const float* W0   = (const float*)d_in[1];
    const float* b0   = (const float*)d_in[2];
    const float* W1   = (const float*)d_in[3];
    const float* b1   = (const float*)d_in[4];
    const float* Wout = (const float*)d_in[5];
    const float* bout = (const float*)d_in[6];
    float* out = (float*)d_out;

    char* ws = (char*)d_ws;
    _Float16* U    = (_Float16*)(ws);                      // 8*225*256*2 =   921,600 B
    _Float16* V    = (_Float16*)(ws + 921600);             //                 921,600 B
    _Float16* W1F  = (_Float16*)(ws + 2 * 921600);         // 256*256*2  =   131,072 B
    float*    accg = (float*)(ws + 2 * 921600 + 131072);   // 8*256*4    =     8,192 B

    prep_kernel<<<392, 256, 0, stream>>>(x, W0, b0, W1, U, V, W1F, accg);
    main_kernel<<<NB * 15 * 9, 256, 0, stream>>>(U, V, W1F, b1, accg);
    out_kernel<<<NB, 128, 0, stream>>>(accg, Wout, bout, out);
}

// Round 19
// 88.345 us; speedup vs baseline: 1.2094x; 1.2094x over previous
//
#include <hip/hip_runtime.h>
#include <hip/hip_bf16.h>
#include <stdint.h>

// Problem constants
#define NB 8
#define NP 225      // patches per image
#define PGRID 15    // 15x15 patch grid
#define DH 256      // hidden
#define DIN 130     // per-node feature dim

typedef _Float16 f16x8 __attribute__((ext_vector_type(8)));   // 8 f16 = 4 VGPRs
typedef float    f32x4 __attribute__((ext_vector_type(4)));

static __device__ __forceinline__ float lrelu(float x) { return fmaxf(x, 0.01f * x); }

// ---------------------------------------------------------------------------
// K1 (fused prep): blocks 0..359 = pool+patch+U/V projection (f32 math, f16
// store) + accg zeroing; blocks 360..391 = W1 repack to fragment-linear f16.
__global__ void prep_kernel(const float* __restrict__ x, const float* __restrict__ W0,
                            const float* __restrict__ b0, const float* __restrict__ W1,
                            _Float16* __restrict__ U, _Float16* __restrict__ V,
                            _Float16* __restrict__ W1F, float* __restrict__ accg) {
    int blk = blockIdx.x;
    if (blk >= 360) {
        int t = (blk - 360) * 256 + threadIdx.x;   // 8192 threads = 128 slots * 64 lanes
        int slot = t >> 6, l = t & 63;
        int nf = slot >> 3, ks = slot & 7;
        int n = nf * 16 + (l & 15);
        int kb = l >> 4;
        f16x8 wv;
        #pragma unroll
        for (int e = 0; e < 8; ++e) {
            int k = ks * 32 + kb * 8 + e;
            wv[e] = (_Float16)W1[k * DH + n];
        }
        reinterpret_cast<f16x8*>(W1F)[t] = wv;
        return;
    }
    int bb = blk / 45;
    int p0 = (blk % 45) * 5;
    if (blk % 45 == 0) accg[bb * DH + threadIdx.x] = 0.0f;   // replaces memset
    __shared__ float fl[5][DIN];
    int t = threadIdx.x;
    for (int idx = t; idx < 5 * DIN; idx += 256) {
        int pp = idx / DIN, f = idx % DIN;
        int p = p0 + pp;
        int r = p / PGRID, c = p % PGRID;
        float val;
        if (f < 128) {
            int ch = f >> 2, q = f & 3, ki = q >> 1, kj = q & 1;
            int R = r + ki, C = c + kj;                 // pooled coords (0..15)
            const float* xp = x + (((size_t)bb * 32 + ch) * 32 + 2 * R) * 32 + 2 * C;
            val = 0.25f * (xp[0] + xp[1] + xp[32] + xp[33]);
        } else {
            val = (f == 128) ? (float)(c - 7) : (float)(r - 7);  // cx, cy
        }
        fl[pp][f] = val;
    }
    __syncthreads();
    int n = t;  // 0..255
    float u[5] = {0, 0, 0, 0, 0}, v[5] = {0, 0, 0, 0, 0};
    for (int k = 0; k < DIN; ++k) {
        float wa = W0[k * DH + n];
        float wb = W0[(DIN + k) * DH + n];
        #pragma unroll
        for (int pp = 0; pp < 5; ++pp) {
            float f = fl[pp][k];
            u[pp] = fmaf(f, wa, u[pp]);
            v[pp] = fmaf(f, wb, v[pp]);
        }
    }
    float bb0 = b0[n];
    #pragma unroll
    for (int pp = 0; pp < 5; ++pp) {
        size_t base = ((size_t)bb * NP + p0 + pp) * DH + n;
        U[base] = (_Float16)(u[pp] + bb0);  // fold b0 into U
        V[base] = (_Float16)v[pp];
    }
}

// ---------------------------------------------------------------------------
// K2: main relational GEMM + reduce — R12 body with MAKESPAN-FIXED grid.
// R12: 1080 blocks over 512 resident slots (2/CU x 256 CU) -> ~56 slots ran
// 3 sequential blocks (21 iters) vs 2 (14) for the rest: ~30% queuing tail.
// CHUNKS=4 x TILESPC=15 -> grid 480 <= 512: all blocks start at t=0.
// R18's NaN was a DMA indexing bug (q*1024/l*16 instead of q*512/l*8 ->
// LDS OOB writes); fixed here. Body otherwise unchanged (R6-R17 lessons:
// no pins, no dbuf, no role-split, no extra persistent regs).
// LDS: Af 32KB + Upad 8.25KB + Vlds 30KB = 71.9KB -> exactly 2 blocks/CU.
__global__ __launch_bounds__(256, 2) void main_kernel(
        const _Float16* __restrict__ U, const _Float16* __restrict__ V,
        const _Float16* __restrict__ W1F, const float* __restrict__ b1,
        float* __restrict__ accg) {
    __shared__ f16x8 Af[2048];            // 32 KB: [mf(4)][ks(8)][lane(64)] x 16B
    __shared__ _Float16 Upad[16 * 264];   // 8.25 KB
    __shared__ _Float16 Vlds[60 * 256];   // 30 KB: chunk's V rows (<=60)
    const int JT = 15, CHUNKS = 4, TILESPC = 15;  // 57 = 15+15+15+12
    int blk = blockIdx.x;
    int bb = blk / (JT * CHUNKS);
    int rem = blk % (JT * CHUNKS);
    int jt = rem / CHUNKS, ch = rem % CHUNKS;
    int j0 = jt * 16;
    int tile0 = ch * TILESPC;
    int nt = min(TILESPC, 57 - tile0);
    int t = threadIdx.x, l = t & 63, w = t >> 6;

    // ---- DMA chunk V rows to LDS: 60 rows x 512B = 30 instrs x 1KB each
    // (instr q covers 512 halfs: 64 lanes x 8 halfs). Tail chunks read past
    // valid rows into ws (harmless; those i-rows masked in epilogue).
    {
        const _Float16* Vsrc = V + ((size_t)bb * NP + tile0 * 4) * DH;
        for (int q = w; q < 30; q += 4) {
            __builtin_amdgcn_global_load_lds(
                (const __attribute__((address_space(1))) void*)(Vsrc + q * 512 + (size_t)l * 8),
                (__attribute__((address_space(3))) void*)(&Vlds[q * 512]),
                16, 0, 0);
        }
    }
    // ---- stage U tile once (f16, coalesced: 16 threads/row x 32B)
    {
        int jj = t >> 4, kk = (t & 15) * 16;   // kk in halfs
        int jc = j0 + jj; if (jc >= NP) jc = NP - 1;
        const f16x8* src = reinterpret_cast<const f16x8*>(U + ((size_t)bb * NP + jc) * DH + kk);
        *reinterpret_cast<f16x8*>(&Upad[jj * 264 + kk])     = src[0];
        *reinterpret_cast<f16x8*>(&Upad[jj * 264 + kk + 8]) = src[1];
    }
    // ---- B fragments (wave's N=64 slice): 32 frags = 128 regs
    f16x8 bv[4][8];
    const f16x8* Bp = reinterpret_cast<const f16x8*>(W1F);
    #pragma unroll
    for (int nf = 0; nf < 4; ++nf)
        #pragma unroll
        for (int ks = 0; ks < 8; ++ks)
            bv[nf][ks] = Bp[((w * 4 + nf) * 8 + ks) * 64 + l];
    float b1v[4];
    #pragma unroll
    for (int nf = 0; nf < 4; ++nf) b1v[nf] = b1[w * 64 + nf * 16 + (l & 15)];
    int rowg = l >> 4;
    float jmask[4];
    #pragma unroll
    for (int r = 0; r < 4; ++r) jmask[r] = (j0 + rowg * 4 + r) < NP ? 1.0f : 0.0f;
    float psum[4] = {0.f, 0.f, 0.f, 0.f};
    int kb = l >> 4;
    const _Float16* Urow = &Upad[(l & 15) * 264 + kb * 8];
    __syncthreads();   // drains vmcnt (Vlds DMA) + makes Upad visible

    for (int itl = 0; itl < nt; ++itl) {
        int i0 = (tile0 + itl) * 4;
        const f16x8* Vrow = reinterpret_cast<const f16x8*>(&Vlds[(itl * 4 + w) * 256]);
        if (itl) __syncthreads();   // prev iter's A reads done before overwrite

        // ---- build A: wave w builds mf=w, 8 ks slots (packed-f16 math)
        #pragma unroll
        for (int ks = 0; ks < 8; ++ks) {
            f16x8 uv = *reinterpret_cast<const f16x8*>(Urow + ks * 32);
            f16x8 vv = Vrow[ks * 4 + kb];
            f16x8 s  = uv + vv;
            f16x8 a  = __builtin_elementwise_max(s, s * (_Float16)0.01f);
            Af[(w * 8 + ks) * 64 + l] = a;
        }
        __syncthreads();

        // ---- MFMA: acc init = b1 (col = lane&15, same for all rows)
        f32x4 acc[4][4];
        #pragma unroll
        for (int mf = 0; mf < 4; ++mf)
            #pragma unroll
            for (int nf = 0; nf < 4; ++nf)
                acc[mf][nf] = (f32x4){b1v[nf], b1v[nf], b1v[nf], b1v[nf]};
        #pragma unroll
        for (int ks = 0; ks < 8; ++ks) {
            f16x8 av[4];
            #pragma unroll
            for (int mf = 0; mf < 4; ++mf) av[mf] = Af[(mf * 8 + ks) * 64 + l];
            #pragma unroll
            for (int mf = 0; mf < 4; ++mf)
                #pragma unroll
                for (int nf = 0; nf < 4; ++nf)
                    acc[mf][nf] = __builtin_amdgcn_mfma_f32_16x16x32_f16(
                        av[mf], bv[nf][ks], acc[mf][nf], 0, 0, 0);
        }

        // ---- epilogue: lrelu + jmask-fma row-sum (wave-uniform mf skip)
        #pragma unroll
        for (int mf = 0; mf < 4; ++mf) {
            if (i0 + mf < NP) {
                #pragma unroll
                for (int r = 0; r < 4; ++r) {
                    #pragma unroll
                    for (int nf = 0; nf < 4; ++nf) {
                        float a = acc[mf][nf][r];
                        float h = fmaxf(a, 0.01f * a);
                        psum[nf] = fmaf(h, jmask[r], psum[nf]);
                    }
                }
            }
        }
    }

    // ---- block-level reduce + one atomicAdd set
    #pragma unroll
    for (int nf = 0; nf < 4; ++nf) {
        psum[nf] += __shfl_xor(psum[nf], 16);
        psum[nf] += __shfl_xor(psum[nf], 32);
    }
    if (l < 16) {
        #pragma unroll
        for (int nf = 0; nf < 4; ++nf)
            atomicAdd(&accg[bb * DH + w * 64 + nf * 16 + l], psum[nf]);
    }
}

// ---------------------------------------------------------------------------
// K3: out[b,o] = (accg[b,:]/P^2) @ Wout + bout
__global__ void out_kernel(const float* __restrict__ accg, const float* __restrict__ Wout,
                           const float* __restrict__ bout, float* __restrict__ out) {
    int bb = blockIdx.x;
    int o = threadIdx.x;  // 0..127
    float s = 0.f;
    for (int n = 0; n < DH; ++n)
        s = fmaf(accg[bb * DH + n], Wout[n * 128 + o], s);
    out[bb * 128 + o] = s * (1.0f / 50625.0f) + bout[o];
}

// ---------------------------------------------------------------------------
extern "C" void kernel_launch(void* const* d_in, const int* in_sizes, int n_in,
                              void* d_out, int out_size, void* d_ws, size_t ws_size,
                              hipStream_t stream) {
    const float* x    = (const float*)d_in[0];
    const float* W0   = (const float*)d_in[1];
    const float* b0   = (const float*)d_in[2];
    const float* W1   = (const float*)d_in[3];
    const float* b1   = (const float*)d_in[4];
    const float* Wout = (const float*)d_in[5];
    const float* bout = (const float*)d_in[6];
    float* out = (float*)d_out;

    char* ws = (char*)d_ws;
    _Float16* U    = (_Float16*)(ws);                      // 8*225*256*2 =   921,600 B
    _Float16* V    = (_Float16*)(ws + 921600);             //                 921,600 B
    _Float16* W1F  = (_Float16*)(ws + 2 * 921600);         // 256*256*2  =   131,072 B
    float*    accg = (float*)(ws + 2 * 921600 + 131072);   // 8*256*4    =     8,192 B

    prep_kernel<<<392, 256, 0, stream>>>(x, W0, b0, W1, U, V, W1F, accg);
    main_kernel<<<NB * 15 * 4, 256, 0, stream>>>(U, V, W1F, b1, accg);
    out_kernel<<<NB, 128, 0, stream>>>(accg, Wout, bout, out);
}

// Round 20
// 85.980 us; speedup vs baseline: 1.2427x; 1.0275x over previous
//
#include <hip/hip_runtime.h>
#include <hip/hip_bf16.h>
#include <stdint.h>

// Problem constants
#define NB 8
#define NP 225      // patches per image
#define PGRID 15    // 15x15 patch grid
#define DH 256      // hidden
#define DIN 130     // per-node feature dim

typedef _Float16 f16x8 __attribute__((ext_vector_type(8)));   // 8 f16 = 4 VGPRs
typedef float    f32x4 __attribute__((ext_vector_type(4)));

static __device__ __forceinline__ float lrelu(float x) { return fmaxf(x, 0.01f * x); }

// ---------------------------------------------------------------------------
// K1 (fused prep): blocks 0..359 = pool+patch+U/V projection (f32 math, f16
// store) + accg zeroing; blocks 360..391 = W1 repack to fragment-linear f16.
__global__ void prep_kernel(const float* __restrict__ x, const float* __restrict__ W0,
                            const float* __restrict__ b0, const float* __restrict__ W1,
                            _Float16* __restrict__ U, _Float16* __restrict__ V,
                            _Float16* __restrict__ W1F, float* __restrict__ accg) {
    int blk = blockIdx.x;
    if (blk >= 360) {
        int t = (blk - 360) * 256 + threadIdx.x;   // 8192 threads = 128 slots * 64 lanes
        int slot = t >> 6, l = t & 63;
        int nf = slot >> 3, ks = slot & 7;
        int n = nf * 16 + (l & 15);
        int kb = l >> 4;
        f16x8 wv;
        #pragma unroll
        for (int e = 0; e < 8; ++e) {
            int k = ks * 32 + kb * 8 + e;
            wv[e] = (_Float16)W1[k * DH + n];
        }
        reinterpret_cast<f16x8*>(W1F)[t] = wv;
        return;
    }
    int bb = blk / 45;
    int p0 = (blk % 45) * 5;
    if (blk % 45 == 0) accg[bb * DH + threadIdx.x] = 0.0f;   // replaces memset
    __shared__ float fl[5][DIN];
    int t = threadIdx.x;
    for (int idx = t; idx < 5 * DIN; idx += 256) {
        int pp = idx / DIN, f = idx % DIN;
        int p = p0 + pp;
        int r = p / PGRID, c = p % PGRID;
        float val;
        if (f < 128) {
            int ch = f >> 2, q = f & 3, ki = q >> 1, kj = q & 1;
            int R = r + ki, C = c + kj;                 // pooled coords (0..15)
            const float* xp = x + (((size_t)bb * 32 + ch) * 32 + 2 * R) * 32 + 2 * C;
            val = 0.25f * (xp[0] + xp[1] + xp[32] + xp[33]);
        } else {
            val = (f == 128) ? (float)(c - 7) : (float)(r - 7);  // cx, cy
        }
        fl[pp][f] = val;
    }
    __syncthreads();
    int n = t;  // 0..255
    float u[5] = {0, 0, 0, 0, 0}, v[5] = {0, 0, 0, 0, 0};
    for (int k = 0; k < DIN; ++k) {
        float wa = W0[k * DH + n];
        float wb = W0[(DIN + k) * DH + n];
        #pragma unroll
        for (int pp = 0; pp < 5; ++pp) {
            float f = fl[pp][k];
            u[pp] = fmaf(f, wa, u[pp]);
            v[pp] = fmaf(f, wb, v[pp]);
        }
    }
    float bb0 = b0[n];
    #pragma unroll
    for (int pp = 0; pp < 5; ++pp) {
        size_t base = ((size_t)bb * NP + p0 + pp) * DH + n;
        U[base] = (_Float16)(u[pp] + bb0);  // fold b0 into U
        V[base] = (_Float16)v[pp];
    }
}

// ---------------------------------------------------------------------------
// K2: main relational GEMM + reduce — CHAMPION (R12 config, 65.7us measured).
// Structure: block = (batch, j-tile 16, chunk of <=7 i-tiles), 4 waves,
// 2 blocks/CU. Wave w: persistent bv = N=64 slice of W1F in 128 regs; builds
// A slots mf=w into Af (frag-linear f16); V chunk DMA'd to LDS once/block;
// U staged once (stride-264). Plain 2-barrier loop.
// Measured structural limit: per block-iter MFMA 2483 + LDS 2690 cyc run
// serially (5340 measured); x29.5 block-iters/CU = 64us floor; we're at 66.
// Overlap attempts all spill: R6/R7/R13/R14/R15/R16/R17 — register geometry
// (bv128+acc64) leaves no room for pipelined state. Do not re-attempt without
// hand-asm AGPR control.
__global__ __launch_bounds__(256, 2) void main_kernel(
        const _Float16* __restrict__ U, const _Float16* __restrict__ V,
        const _Float16* __restrict__ W1F, const float* __restrict__ b1,
        float* __restrict__ accg) {
    __shared__ f16x8 Af[2048];            // 32 KB: [mf(4)][ks(8)][lane(64)] x 16B
    __shared__ _Float16 Upad[16 * 264];   // 8.25 KB; stride 264h
    __shared__ _Float16 Vlds[28 * 256];   // 14 KB: chunk's V rows
    const int JT = 15, CHUNKS = 9, TILESPC = 7;  // 9*7=63 >= 57 i-tiles
    int blk = blockIdx.x;
    int bb = blk / (JT * CHUNKS);
    int rem = blk % (JT * CHUNKS);
    int jt = rem / CHUNKS, ch = rem % CHUNKS;
    int j0 = jt * 16;
    int tile0 = ch * TILESPC;
    int nt = min(TILESPC, 57 - tile0);
    int t = threadIdx.x, l = t & 63, w = t >> 6;

    // ---- DMA chunk V rows to LDS: 28 rows x 512B = 14 x 1KB instrs.
    // Rows contiguous in V; tail chunks read past valid rows into ws
    // scratch (harmless; masked in epilogue).
    {
        const _Float16* Vsrc = V + ((size_t)bb * NP + tile0 * 4) * DH;
        for (int q = w * 4; q < 14 && q < w * 4 + 4; ++q) {
            __builtin_amdgcn_global_load_lds(
                (const __attribute__((address_space(1))) void*)(Vsrc + q * 512 + (size_t)l * 8),
                (__attribute__((address_space(3))) void*)(&Vlds[q * 512]),
                16, 0, 0);
        }
    }
    // ---- stage U tile once (f16, coalesced: 16 threads/row x 32B)
    {
        int jj = t >> 4, kk = (t & 15) * 16;   // kk in halfs
        int jc = j0 + jj; if (jc >= NP) jc = NP - 1;
        const f16x8* src = reinterpret_cast<const f16x8*>(U + ((size_t)bb * NP + jc) * DH + kk);
        *reinterpret_cast<f16x8*>(&Upad[jj * 264 + kk])     = src[0];
        *reinterpret_cast<f16x8*>(&Upad[jj * 264 + kk + 8]) = src[1];
    }
    // ---- B fragments (wave's N=64 slice): 32 frags = 128 regs
    f16x8 bv[4][8];
    const f16x8* Bp = reinterpret_cast<const f16x8*>(W1F);
    #pragma unroll
    for (int nf = 0; nf < 4; ++nf)
        #pragma unroll
        for (int ks = 0; ks < 8; ++ks)
            bv[nf][ks] = Bp[((w * 4 + nf) * 8 + ks) * 64 + l];
    float b1v[4];
    #pragma unroll
    for (int nf = 0; nf < 4; ++nf) b1v[nf] = b1[w * 64 + nf * 16 + (l & 15)];
    float psum[4] = {0.f, 0.f, 0.f, 0.f};
    int kb = l >> 4;
    const _Float16* Urow = &Upad[(l & 15) * 264 + kb * 8];
    __syncthreads();   // drains vmcnt (Vlds DMA) + makes Upad visible

    for (int itl = 0; itl < nt; ++itl) {
        // pin bv (kept from the measured champion build verbatim)
        #pragma unroll
        for (int nf = 0; nf < 4; ++nf)
            #pragma unroll
            for (int ks = 0; ks < 8; ++ks)
                asm volatile("" : "+v"(bv[nf][ks]));

        int i0 = (tile0 + itl) * 4;
        int vrow = itl * 4 + w;     // wave w builds mf=w
        const f16x8* Vrow = reinterpret_cast<const f16x8*>(&Vlds[vrow * 256]);
        if (itl) __syncthreads();   // prev iter's A reads done before overwrite

        // ---- build A: wave w builds mf=w, 8 ks slots (packed-f16 math)
        #pragma unroll
        for (int ks = 0; ks < 8; ++ks) {
            f16x8 uv = *reinterpret_cast<const f16x8*>(Urow + ks * 32);
            f16x8 vv = Vrow[ks * 4 + kb];
            f16x8 s  = uv + vv;
            f16x8 a  = __builtin_elementwise_max(s, s * (_Float16)0.01f);
            Af[(w * 8 + ks) * 64 + l] = a;
        }
        __syncthreads();

        // ---- MFMA: acc init = b1 (col = lane&15, same for all rows)
        f32x4 acc[4][4];
        #pragma unroll
        for (int mf = 0; mf < 4; ++mf)
            #pragma unroll
            for (int nf = 0; nf < 4; ++nf)
                acc[mf][nf] = (f32x4){b1v[nf], b1v[nf], b1v[nf], b1v[nf]};
        #pragma unroll
        for (int ks = 0; ks < 8; ++ks) {
            f16x8 av[4];
            #pragma unroll
            for (int mf = 0; mf < 4; ++mf) av[mf] = Af[(mf * 8 + ks) * 64 + l];
            #pragma unroll
            for (int mf = 0; mf < 4; ++mf)
                #pragma unroll
                for (int nf = 0; nf < 4; ++nf)
                    acc[mf][nf] = __builtin_amdgcn_mfma_f32_16x16x32_f16(
                        av[mf], bv[nf][ks], acc[mf][nf], 0, 0, 0);
        }

        // ---- epilogue: lrelu + masked row-sum into psum (held across iters)
        int rowg = l >> 4;  // C row = rowg*4 + r
        #pragma unroll
        for (int mf = 0; mf < 4; ++mf) {
            bool iv = (i0 + mf) < NP;
            #pragma unroll
            for (int r = 0; r < 4; ++r) {
                bool valid = iv && ((j0 + rowg * 4 + r) < NP);
                #pragma unroll
                for (int nf = 0; nf < 4; ++nf) {
                    float h = lrelu(acc[mf][nf][r]);
                    psum[nf] += valid ? h : 0.f;
                }
            }
        }
    }

    // ---- block-level reduce + one atomicAdd set
    #pragma unroll
    for (int nf = 0; nf < 4; ++nf) {
        psum[nf] += __shfl_xor(psum[nf], 16);
        psum[nf] += __shfl_xor(psum[nf], 32);
    }
    if (l < 16) {
        #pragma unroll
        for (int nf = 0; nf < 4; ++nf)
            atomicAdd(&accg[bb * DH + w * 64 + nf * 16 + l], psum[nf]);
    }
}

// ---------------------------------------------------------------------------
// K3: out[b,o] = (accg[b,:]/P^2) @ Wout + bout
__global__ void out_kernel(const float* __restrict__ accg, const float* __restrict__ Wout,
                           const float* __restrict__ bout, float* __restrict__ out) {
    int bb = blockIdx.x;
    int o = threadIdx.x;  // 0..127
    float s = 0.f;
    for (int n = 0; n < DH; ++n)
        s = fmaf(accg[bb * DH + n], Wout[n * 128 + o], s);
    out[bb * 128 + o] = s * (1.0f / 50625.0f) + bout[o];
}

// ---------------------------------------------------------------------------
extern "C" void kernel_launch(void* const* d_in, const int* in_sizes, int n_in,
                              void* d_out, int out_size, void* d_ws, size_t ws_size,
                              hipStream_t stream) {
    const float* x    = (const float*)d_in[0];
    const float* W0   = (const float*)d_in[1];
    const float* b0   = (const float*)d_in[2];
    const float* W1   = (const float*)d_in[3];
    const float* b1   = (const float*)d_in[4];
    const float* Wout = (const float*)d_in[5];
    const float* bout = (const float*)d_in[6];
    float* out = (float*)d_out;

    char* ws = (char*)d_ws;
    _Float16* U    = (_Float16*)(ws);                      // 8*225*256*2 =   921,600 B
    _Float16* V    = (_Float16*)(ws + 921600);             //                 921,600 B
    _Float16* W1F  = (_Float16*)(ws + 2 * 921600);         // 256*256*2  =   131,072 B
    float*    accg = (float*)(ws + 2 * 921600 + 131072);   // 8*256*4    =     8,192 B

    prep_kernel<<<392, 256, 0, stream>>>(x, W0, b0, W1, U, V, W1F, accg);
    main_kernel<<<NB * 15 * 9, 256, 0, stream>>>(U, V, W1F, b1, accg);
    out_kernel<<<NB, 128, 0, stream>>>(accg, Wout, bout, out);
}